// Round 20
// baseline (559.299 us; speedup 1.0000x reference)
//
#include <hip/hip_runtime.h>
#include <hip/hip_bf16.h>

// Problem constants (B=2, M=2048, HS=1024, K=16 heads, D=64)
#define MM   2048
#define HSZ  1024
#define KH   16
#define DH   64

typedef __attribute__((ext_vector_type(8))) short bf16x8;
typedef __attribute__((ext_vector_type(4))) float f32x4;
typedef __attribute__((ext_vector_type(8))) unsigned short u16x8;

#define GLOAD_LDS16(gp, lp) \
    __builtin_amdgcn_global_load_lds( \
        (const __attribute__((address_space(1))) unsigned int*)(gp), \
        (__attribute__((address_space(3))) unsigned int*)(lp), 16, 0, 0)

__device__ __forceinline__ unsigned short f2bf(float x) {
    union { float f; unsigned u; } v; v.f = x;
    unsigned r = v.u + 0x7FFFu + ((v.u >> 16) & 1u);
    return (unsigned short)(r >> 16);
}

// ---- hand-rolled grid barrier (all 1024 blocks co-resident by capacity math) ----
// bar[0..2]: arrival counters (zeroed each call); bar[3]: release flag.
__device__ __forceinline__ void grid_bar(int* bar, int k) {
    __syncthreads();
    if (threadIdx.x == 0) {
        __threadfence();   // release: make this block's stores visible (agent scope)
        int old = __hip_atomic_fetch_add(&bar[k], 1, __ATOMIC_ACQ_REL, __HIP_MEMORY_SCOPE_AGENT);
        if (old == (int)gridDim.x - 1) {
            __hip_atomic_store(&bar[3], k + 1, __ATOMIC_RELEASE, __HIP_MEMORY_SCOPE_AGENT);
        } else {
            int guard = 0;
            while (__hip_atomic_load(&bar[3], __ATOMIC_ACQUIRE, __HIP_MEMORY_SCOPE_AGENT) < k + 1) {
                __builtin_amdgcn_s_sleep(8);
                if (++guard > (1 << 20)) break;   // hang-breaker (~0.2 s)
            }
        }
        __threadfence();   // acquire: invalidate stale caches before reading others' data
    }
    __syncthreads();
}

// ---------------- GEMM core, 64x64 tile (R15 structure, unchanged) ----------------
#define SROW(li) ((li) >> 3)
#define SCOL(li) ((((li) & 7) ^ (SROW(li) & 7)) * 8)

template<int STORE_BF16>
__device__ __forceinline__ void gemm_core64(
    unsigned short* __restrict__ AsB, unsigned short* __restrict__ BsB,   // each [2][4096]
    const unsigned short* __restrict__ A, const unsigned short* __restrict__ Bm,
    void* __restrict__ Cv, int N, int Kd,
    int bx, int by, int bz, long aZ, long bZ, long cZ)
{
    const unsigned short* Ab = A  + bz * aZ;
    const unsigned short* Bb = Bm + bz * bZ;
    long czoff = bz * cZ;
    int row0 = by * 64;
    int col0 = bx * 64;
    int t = threadIdx.x;
    int wid = t >> 6, l = t & 63;
    int wr = wid >> 1, wc = wid & 1;
    int lr = l & 15, lhi = l >> 4;

    #define STAGE64(buf, k0s) do { \
        unsigned short* As_ = AsB + (buf) * 4096; \
        unsigned short* Bs_ = BsB + (buf) * 4096; \
        int a0 = t, a1 = t + 256; \
        GLOAD_LDS16(Ab + (long)(row0 + SROW(a0)) * Kd + (k0s) + SCOL(a0), As_ + a0 * 8); \
        GLOAD_LDS16(Ab + (long)(row0 + SROW(a1)) * Kd + (k0s) + SCOL(a1), As_ + a1 * 8); \
        GLOAD_LDS16(Bb + (long)(col0 + SROW(a0)) * Kd + (k0s) + SCOL(a0), Bs_ + a0 * 8); \
        GLOAD_LDS16(Bb + (long)(col0 + SROW(a1)) * Kd + (k0s) + SCOL(a1), Bs_ + a1 * 8); \
    } while (0)

    f32x4 acc[2][2] = {};
    int nk = Kd >> 6;

    STAGE64(0, 0);

    for (int ks = 0; ks < nk; ++ks) {
        int cur = ks & 1;
        if (ks + 1 < nk) {
            STAGE64(cur ^ 1, (ks + 1) << 6);
            asm volatile("s_waitcnt vmcnt(4)" ::: "memory");
        } else {
            asm volatile("s_waitcnt vmcnt(0)" ::: "memory");
        }
        __builtin_amdgcn_s_barrier();

        bf16x8 af[2][2], bfr[2][2];
        #pragma unroll
        for (int kk = 0; kk < 2; ++kk) {
            int slotx = ((kk * 4 + lhi) ^ (lr & 7)) << 3;
            #pragma unroll
            for (int i = 0; i < 2; ++i)
                af[kk][i] = *(const bf16x8*)(AsB + cur * 4096 + (wr * 32 + i * 16 + lr) * 64 + slotx);
            #pragma unroll
            for (int j = 0; j < 2; ++j)
                bfr[kk][j] = *(const bf16x8*)(BsB + cur * 4096 + (wc * 32 + j * 16 + lr) * 64 + slotx);
        }
        asm volatile("s_waitcnt lgkmcnt(0)" ::: "memory");
        __builtin_amdgcn_sched_barrier(0);
        __builtin_amdgcn_s_barrier();

        #pragma unroll
        for (int kk = 0; kk < 2; ++kk)
            #pragma unroll
            for (int i = 0; i < 2; ++i)
                #pragma unroll
                for (int j = 0; j < 2; ++j)
                    acc[i][j] = __builtin_amdgcn_mfma_f32_16x16x32_bf16(af[kk][i], bfr[kk][j], acc[i][j], 0, 0, 0);
    }
    #undef STAGE64

    #pragma unroll
    for (int i = 0; i < 2; ++i) {
        int rbase = row0 + wr * 32 + i * 16 + lhi * 4;
        #pragma unroll
        for (int j = 0; j < 2; ++j) {
            int cidx = col0 + wc * 32 + j * 16 + lr;
            #pragma unroll
            for (int r_ = 0; r_ < 4; ++r_) {
                long idx = czoff + (long)(rbase + r_) * N + cidx;
                if (STORE_BF16) ((unsigned short*)Cv)[idx] = f2bf(acc[i][j][r_]);
                else            ((float*)Cv)[idx] = acc[i][j][r_];
            }
        }
    }
}

// ---------------- counting sort of rows by mean/64 (one bk per call) ----------------
__device__ void sort_core(char* smem, const float* __restrict__ mean_,
                          int* __restrict__ perm, int bk)
{
    unsigned short (*hist)[257] = (unsigned short(*)[257])smem;
    int* binTot = (int*)(smem + 16448);
    int* binStart = binTot + 32;
    int t = threadIdx.x;
    int bins[8];
    #pragma unroll
    for (int i = 0; i < 8; ++i) {
        float mq = mean_[bk * MM + t * 8 + i];
        int b = (int)(mq * (1.f / 64.f));
        bins[i] = min(31, max(0, b));
    }
    for (int b = 0; b < 32; ++b) hist[b][t] = 0;
    __syncthreads();
    #pragma unroll
    for (int i = 0; i < 8; ++i) hist[bins[i]][t]++;
    __syncthreads();
    int w = t >> 6, l = t & 63;
    for (int b = w * 8; b < w * 8 + 8; ++b) {
        int carry = 0;
        for (int g = 0; g < 4; ++g) {
            int v = (int)hist[b][g * 64 + l];
            int x = v;
            #pragma unroll
            for (int off = 1; off < 64; off <<= 1) {
                int y = __shfl_up(x, off, 64);
                if (l >= off) x += y;
            }
            hist[b][g * 64 + l] = (unsigned short)(x - v + carry);
            carry += __shfl(x, 63, 64);
        }
        if (l == 0) binTot[b] = carry;
    }
    __syncthreads();
    if (t == 0) {
        int s = 0;
        for (int b = 0; b < 32; ++b) { binStart[b] = s; s += binTot[b]; }
    }
    __syncthreads();
    #pragma unroll
    for (int i = 0; i < 8; ++i) {
        int b = bins[i];
        int prior = 0;
        #pragma unroll
        for (int j = 0; j < 8; ++j) if (j < i && bins[j] == b) prior++;
        int pos = binStart[b] + (int)hist[b][t] + prior;
        perm[bk * MM + pos] = t * 8 + i;
    }
}

// ================= mega-kernel (NORMAL launch): 4 phases, 1024 blocks x 256 =================
__global__ __launch_bounds__(256, 4) void mega(
    const float* __restrict__ h, const float* __restrict__ Wspan,
    const float* __restrict__ Wval, const float* __restrict__ Wout,
    float* __restrict__ mean_, float* __restrict__ soft_,
    unsigned short* __restrict__ h_bf,
    unsigned short* __restrict__ Wval_bf, unsigned short* __restrict__ Wout_bf,
    unsigned short* __restrict__ hvT, unsigned short* __restrict__ att,
    int* __restrict__ perm, float* __restrict__ out, int* __restrict__ bar)
{
    __shared__ __align__(16) char smem[32768];
    int f = blockIdx.x, t = threadIdx.x;
    int wid = t >> 6, l = t & 63;
    int lr = l & 15, lhi = l >> 4;

    // =========== PHASE 1: span split-K MFMA (0..255) || converts (256..1023) ===========
    if (f < 256) {
        float (*red)[16][33] = (float(*)[16][33])smem;
        int m0 = f * 16;
        const float* hrow = h + (long)(m0 + lr) * HSZ + wid * 256;
        f32x4 acc[2] = {};

        #define SPLIT8(af_, hh_, hl_) { \
            _Pragma("unroll") for (int j_ = 0; j_ < 8; ++j_) { \
                unsigned short hu_ = f2bf(af_[j_]); \
                union { unsigned u; float f; } cv_; cv_.u = (unsigned)hu_ << 16; \
                hh_[j_] = (short)hu_; hl_[j_] = (short)f2bf(af_[j_] - cv_.f); } }

        #pragma unroll
        for (int ks = 0; ks < 8; ++ks) {
            int k0 = ks * 32 + lhi * 8;
            float4 a0 = *(const float4*)(hrow + k0);
            float4 a1 = *(const float4*)(hrow + k0 + 4);
            float af[8] = {a0.x, a0.y, a0.z, a0.w, a1.x, a1.y, a1.z, a1.w};
            bf16x8 hh, hl;
            SPLIT8(af, hh, hl);
            #pragma unroll
            for (int ct = 0; ct < 2; ++ct) {
                const float* wrow = Wspan + (long)(ct * 16 + lr) * HSZ + wid * 256 + k0;
                float4 w0 = *(const float4*)wrow;
                float4 w1 = *(const float4*)(wrow + 4);
                float wf[8] = {w0.x, w0.y, w0.z, w0.w, w1.x, w1.y, w1.z, w1.w};
                bf16x8 wh, wl;
                SPLIT8(wf, wh, wl);
                acc[ct] = __builtin_amdgcn_mfma_f32_16x16x32_bf16(hh, wh, acc[ct], 0, 0, 0);
                acc[ct] = __builtin_amdgcn_mfma_f32_16x16x32_bf16(hh, wl, acc[ct], 0, 0, 0);
                acc[ct] = __builtin_amdgcn_mfma_f32_16x16x32_bf16(hl, wh, acc[ct], 0, 0, 0);
            }
        }
        #undef SPLIT8

        #pragma unroll
        for (int ct = 0; ct < 2; ++ct)
            #pragma unroll
            for (int r_ = 0; r_ < 4; ++r_)
                red[wid][lhi * 4 + r_][ct * 16 + lr] = acc[ct][r_];
        __syncthreads();

        int r = t >> 4, o2 = t & 15;
        #pragma unroll
        for (int half = 0; half < 2; ++half) {
            int o = half * 16 + o2;
            float s = red[0][r][o] + red[1][r][o] + red[2][r][o] + red[3][r][o];
            int m = m0 + r;
            int bb = m >> 11, mm = m & 2047;
            int bk = bb * KH + (o >> 1);
            if (!(o & 1)) mean_[bk * MM + mm] = (1.f / (1.f + __expf(-s))) * (float)MM;
            else          soft_[bk * MM + mm] = (s > 15.f) ? s : log1pf(__expf(s));
        }
    } else {
        int bid = f - 256;                   // 768 convert blocks, 8 float4/thread
        #pragma unroll
        for (int i = 0; i < 8; ++i) {
            int fi = bid * 2048 + i * 256 + t;   // float4 id, 0..1572863
            const float* in; unsigned short* outp; int off;
            if (fi < 1048576)      { in = h;    outp = h_bf;    off = fi; }
            else if (fi < 1310720) { in = Wval; outp = Wval_bf; off = fi - 1048576; }
            else                   { in = Wout; outp = Wout_bf; off = fi - 1310720; }
            float4 v = *(const float4*)(in + (long)off * 4);
            ushort4 o4;
            o4.x = f2bf(v.x); o4.y = f2bf(v.y); o4.z = f2bf(v.z); o4.w = f2bf(v.w);
            *(ushort4*)(outp + (long)off * 4) = o4;
        }
    }

    grid_bar(bar, 0);

    // =========== PHASE 2: value GEMM (all 1024) + sort (blocks 992..1023 extra duty) ===========
    {
        int swz = (f & 7) * 128 + (f >> 3);
        int by = swz & 15, r = swz >> 4;
        int bx = r & 31, bz = r >> 5;
        gemm_core64<1>((unsigned short*)smem, (unsigned short*)(smem + 16384),
                       Wval_bf, h_bf, hvT, MM, HSZ, bx, by, bz,
                       0L, (long)MM * HSZ, (long)HSZ * MM);
        if (f >= 992) {
            __syncthreads();
            sort_core(smem, mean_, perm, f - 992);
        }
    }

    grid_bar(bar, 1);

    // =========== PHASE 3: Gaussian attention, 64 sorted rows/block (1024 blocks) ===========
    {
        unsigned short (*Vs)[4096] = (unsigned short(*)[4096])smem;   // 16 KB
        float (*redw)[4] = (float(*)[4])(smem + 16384);
        int swz = (f & 7) * 128 + (f >> 3);
        int bk = swz >> 5;                   // 0..31
        int qb = swz & 31;                   // 0..31
        int b = bk >> 4, head = bk & 15;
        int slot = qb * 64 + wid * 16 + lr;
        int q = perm[bk * MM + slot];
        float mq = mean_[bk * MM + q];
        float sq = soft_[bk * MM + q];
        const unsigned short* Vbase = hvT + (long)bk * DH * MM;

        float w = __fsqrt_rn(50.f / sq);
        float lo = mq - w, hi = mq + w;
        #pragma unroll
        for (int off = 1; off < 64; off <<= 1) {
            lo = fminf(lo, __shfl_xor(lo, off, 64));
            hi = fmaxf(hi, __shfl_xor(hi, off, 64));
        }
        if (l == 0) { redw[0][wid] = lo; redw[1][wid] = hi; }
        __syncthreads();
        float blo = redw[0][0], bhi = redw[1][0];
        #pragma unroll
        for (int i = 1; i < 4; ++i) {
            blo = fminf(blo, redw[0][i]);
            bhi = fmaxf(bhi, redw[1][i]);
        }
        blo = fmaxf(blo, 0.f);
        bhi = fmaxf(fminf(bhi, 2047.f), 0.f);
        int kt0 = ((int)blo) >> 6;
        int kt1 = ((int)bhi) >> 6;
        if (kt1 < kt0) kt1 = kt0;

        f32x4 acc[4] = {};
        float lsum = 0.f;
        int jlane0 = lhi * 8;

        #define VSTAGE(cur, k0s) { \
            int li0 = t, li1 = t + 256; \
            int sr0 = li0 >> 3, sr1 = li1 >> 3; \
            int sc0 = (((li0 & 7) ^ (sr0 & 7)) * 8), sc1 = (((li1 & 7) ^ (sr1 & 7)) * 8); \
            GLOAD_LDS16(Vbase + (long)sr0 * MM + (k0s) + sc0, &Vs[cur][li0 * 8]); \
            GLOAD_LDS16(Vbase + (long)sr1 * MM + (k0s) + sc1, &Vs[cur][li1 * 8]); }

        VSTAGE(0, kt0 << 6);
        __syncthreads();

        for (int kt = kt0; kt <= kt1; ++kt) {
            int cur = (kt - kt0) & 1;
            int k0 = kt << 6;
            if (kt < kt1) VSTAGE(cur ^ 1, k0 + 64);

            float dmin = fmaxf(fmaxf((float)k0 - mq, mq - (float)(k0 + 63)), 0.f);
            bool active = (sq * dmin * dmin) < 50.f;   // exp(-50) ~ 2e-22
            if (__ballot(active)) {
                #pragma unroll
                for (int kk = 0; kk < 64; kk += 32) {
                    bf16x8 pfrag;
                    float dbase = (float)(k0 + kk + jlane0) - mq;
                    #pragma unroll
                    for (int jj = 0; jj < 8; ++jj) {
                        float d_ = dbase + (float)jj;
                        float p = __expf(-sq * d_ * d_);
                        lsum += p;
                        pfrag[jj] = (short)f2bf(p);
                    }
                    int slotx = (((kk >> 3) + lhi) ^ (lr & 7)) << 3;
                    #pragma unroll
                    for (int df = 0; df < 4; ++df) {
                        bf16x8 vf = *(const bf16x8*)&Vs[cur][(df * 16 + lr) * 64 + slotx];
                        acc[df] = __builtin_amdgcn_mfma_f32_16x16x32_bf16(pfrag, vf, acc[df], 0, 0, 0);
                    }
                }
            }
            __syncthreads();
        }
        #undef VSTAGE

        lsum += __shfl_xor(lsum, 16, 64);
        lsum += __shfl_xor(lsum, 32, 64);

        int slot_base = qb * 64 + wid * 16;
        #pragma unroll
        for (int r_ = 0; r_ < 4; ++r_) {
            int qr = lhi * 4 + r_;
            float inv = 1.f / __shfl(lsum, qr, 64);
            int qo = perm[bk * MM + slot_base + qr];
            long orow = ((long)b * MM + qo) * HSZ + head * DH;
            #pragma unroll
            for (int df = 0; df < 4; ++df)
                att[orow + df * 16 + lr] = f2bf(acc[df][r_] * inv);
        }
    }

    grid_bar(bar, 2);

    // =========== PHASE 4: output GEMM (1024 tiles) ===========
    {
        int swz = (f & 7) * 128 + (f >> 3);
        int bx = swz & 15, by = (swz >> 4) & 63;
        gemm_core64<0>((unsigned short*)smem, (unsigned short*)(smem + 16384),
                       att, Wout_bf, out, HSZ, HSZ, bx, by, 0, 0L, 0L, 0L);
    }
}

extern "C" void kernel_launch(void* const* d_in, const int* in_sizes, int n_in,
                              void* d_out, int out_size, void* d_ws, size_t ws_size,
                              hipStream_t stream) {
    (void)in_sizes; (void)n_in; (void)out_size; (void)ws_size;
    const float* h     = (const float*)d_in[0];   // (2, 2048, 1024)
    const float* Wspan = (const float*)d_in[1];   // (32, 1024)
    const float* Wval  = (const float*)d_in[2];   // (1024, 1024)
    const float* Wout  = (const float*)d_in[3];   // (1024, 1024)
    float* out = (float*)d_out;                   // (2, 2048, 1024) f32

    char* ws = (char*)d_ws;
    unsigned short* h_bf    = (unsigned short*)(ws);               // 8 MB
    unsigned short* Wval_bf = (unsigned short*)(ws +  8388608);    // 2 MB
    unsigned short* Wout_bf = (unsigned short*)(ws + 10485760);    // 2 MB
    unsigned short* hvT     = (unsigned short*)(ws + 12582912);    // 8 MB
    unsigned short* att     = (unsigned short*)(ws + 20971520);    // 8 MB
    float*          mean_   = (float*)(ws + 29360128);             // 256 KB
    float*          soft_   = (float*)(ws + 29622272);             // 256 KB
    int*            perm    = (int*)(ws + 29884416);               // 256 KB
    int*            bar     = (int*)(ws + 30146560);               // 16 B

    hipMemsetAsync(bar, 0, 16, stream);   // reset barrier counters each call (graph-capturable)

    mega<<<1024, 256, 0, stream>>>(h, Wspan, Wval, Wout,
                                   mean_, soft_, h_bf, Wval_bf, Wout_bf,
                                   hvT, att, perm, out, bar);
}

// Round 21
// 65.847 us; speedup vs baseline: 8.4939x; 8.4939x over previous
//
#include <hip/hip_runtime.h>
#include <hip/hip_bf16.h>

// Problem constants (B=2, M=2048, HS=1024, K=16 heads, D=64)
#define MM   2048
#define HSZ  1024
#define KH   16
#define DH   64

typedef __attribute__((ext_vector_type(8))) short bf16x8;
typedef __attribute__((ext_vector_type(4))) float f32x4;
typedef __attribute__((ext_vector_type(8))) unsigned short u16x8;

#define GLOAD_LDS16(gp, lp) \
    __builtin_amdgcn_global_load_lds( \
        (const __attribute__((address_space(1))) unsigned int*)(gp), \
        (__attribute__((address_space(3))) unsigned int*)(lp), 16, 0, 0)

__device__ __forceinline__ unsigned short f2bf(float x) {
    union { float f; unsigned u; } v; v.f = x;
    unsigned r = v.u + 0x7FFFu + ((v.u >> 16) & 1u);
    return (unsigned short)(r >> 16);
}

// ================= L1: span split-K MFMA (blocks 0..255) || converts (256..1791) =================
// span: s = h.w via bf16-split 3-product (hi*whi + hi*wlo + lo*whi), f32 MFMA accum.
// 256 blocks x 16 rows; wave w of 4 owns K-quarter [w*256,(w+1)*256) -> 1024 indep waves,
// 8 K-steps each. No LDS staging (each element read once); 8KB LDS tree-reduce of partials.
__global__ __launch_bounds__(256) void pre_fused(
    const float* __restrict__ h, const float* __restrict__ Wspan,
    const float* __restrict__ Wval, const float* __restrict__ Wout,
    float* __restrict__ mean_, float* __restrict__ soft_,
    unsigned short* __restrict__ h_bf,
    unsigned short* __restrict__ Wval_bf, unsigned short* __restrict__ Wout_bf)
{
    __shared__ float red[4][16][33];         // [kq][m-row][o], +1 pad
    int t = threadIdx.x;

    if (blockIdx.x >= 256) {                 // ---- converts: h/Wval/Wout -> bf16 ----
        int bid = blockIdx.x - 256;
        #pragma unroll
        for (int i = 0; i < 4; ++i) {
            int fi = bid * 1024 + i * 256 + t;   // float4 id, 0..1572863
            const float* in; unsigned short* out; int off;
            if (fi < 1048576)      { in = h;    out = h_bf;    off = fi; }
            else if (fi < 1310720) { in = Wval; out = Wval_bf; off = fi - 1048576; }
            else                   { in = Wout; out = Wout_bf; off = fi - 1310720; }
            float4 v = *(const float4*)(in + (long)off * 4);
            ushort4 o4;
            o4.x = f2bf(v.x); o4.y = f2bf(v.y); o4.z = f2bf(v.z); o4.w = f2bf(v.w);
            *(ushort4*)(out + (long)off * 4) = o4;
        }
        return;
    }

    // ---- span block: 16 rows, wave = K-quarter ----
    int blk = blockIdx.x;
    int wid = t >> 6, l = t & 63;
    int lr = l & 15, lhi = l >> 4;
    int m0 = blk * 16;
    const float* hrow = h + (long)(m0 + lr) * HSZ + wid * 256;

    f32x4 acc[2] = {};

    #define SPLIT8(af_, hh_, hl_) { \
        _Pragma("unroll") for (int j_ = 0; j_ < 8; ++j_) { \
            unsigned short hu_ = f2bf(af_[j_]); \
            union { unsigned u; float f; } cv_; cv_.u = (unsigned)hu_ << 16; \
            hh_[j_] = (short)hu_; hl_[j_] = (short)f2bf(af_[j_] - cv_.f); } }

    #pragma unroll
    for (int ks = 0; ks < 8; ++ks) {
        int k0 = ks * 32 + lhi * 8;
        float4 a0 = *(const float4*)(hrow + k0);
        float4 a1 = *(const float4*)(hrow + k0 + 4);
        float af[8] = {a0.x, a0.y, a0.z, a0.w, a1.x, a1.y, a1.z, a1.w};
        bf16x8 hh, hl;
        SPLIT8(af, hh, hl);
        #pragma unroll
        for (int ct = 0; ct < 2; ++ct) {
            const float* wrow = Wspan + (long)(ct * 16 + lr) * HSZ + wid * 256 + k0;
            float4 w0 = *(const float4*)wrow;
            float4 w1 = *(const float4*)(wrow + 4);
            float wf[8] = {w0.x, w0.y, w0.z, w0.w, w1.x, w1.y, w1.z, w1.w};
            bf16x8 wh, wl;
            SPLIT8(wf, wh, wl);
            acc[ct] = __builtin_amdgcn_mfma_f32_16x16x32_bf16(hh, wh, acc[ct], 0, 0, 0);
            acc[ct] = __builtin_amdgcn_mfma_f32_16x16x32_bf16(hh, wl, acc[ct], 0, 0, 0);
            acc[ct] = __builtin_amdgcn_mfma_f32_16x16x32_bf16(hl, wh, acc[ct], 0, 0, 0);
        }
    }
    #undef SPLIT8

    // partials -> LDS  (D layout: row = lhi*4 + r_, col = lr)
    #pragma unroll
    for (int ct = 0; ct < 2; ++ct)
        #pragma unroll
        for (int r_ = 0; r_ < 4; ++r_)
            red[wid][lhi * 4 + r_][ct * 16 + lr] = acc[ct][r_];
    __syncthreads();

    // reduce 4 quarters + activation
    int r = t >> 4, o2 = t & 15;
    #pragma unroll
    for (int half = 0; half < 2; ++half) {
        int o = half * 16 + o2;
        float s = red[0][r][o] + red[1][r][o] + red[2][r][o] + red[3][r][o];
        int m = m0 + r;
        int bb = m >> 11, mm = m & 2047;
        int bk = bb * KH + (o >> 1);
        if (!(o & 1)) mean_[bk * MM + mm] = (1.f / (1.f + __expf(-s))) * (float)MM;
        else          soft_[bk * MM + mm] = (s > 15.f) ? s : log1pf(__expf(s));
    }
}

// ---------------- shared GEMM core, 64x64 tile ----------------
#define SROW(li) ((li) >> 3)
#define SCOL(li) ((((li) & 7) ^ (SROW(li) & 7)) * 8)

template<int STORE_BF16>
__device__ __forceinline__ void gemm_core64(
    unsigned short* __restrict__ AsB, unsigned short* __restrict__ BsB,   // each [2][4096]
    const unsigned short* __restrict__ A, const unsigned short* __restrict__ Bm,
    void* __restrict__ Cv, int N, int Kd,
    int bx, int by, int bz, long aZ, long bZ, long cZ)
{
    const unsigned short* Ab = A  + bz * aZ;
    const unsigned short* Bb = Bm + bz * bZ;
    long czoff = bz * cZ;
    int row0 = by * 64;
    int col0 = bx * 64;
    int t = threadIdx.x;
    int wid = t >> 6, l = t & 63;
    int wr = wid >> 1, wc = wid & 1;
    int lr = l & 15, lhi = l >> 4;

    #define STAGE64(buf, k0s) do { \
        unsigned short* As_ = AsB + (buf) * 4096; \
        unsigned short* Bs_ = BsB + (buf) * 4096; \
        int a0 = t, a1 = t + 256; \
        GLOAD_LDS16(Ab + (long)(row0 + SROW(a0)) * Kd + (k0s) + SCOL(a0), As_ + a0 * 8); \
        GLOAD_LDS16(Ab + (long)(row0 + SROW(a1)) * Kd + (k0s) + SCOL(a1), As_ + a1 * 8); \
        GLOAD_LDS16(Bb + (long)(col0 + SROW(a0)) * Kd + (k0s) + SCOL(a0), Bs_ + a0 * 8); \
        GLOAD_LDS16(Bb + (long)(col0 + SROW(a1)) * Kd + (k0s) + SCOL(a1), Bs_ + a1 * 8); \
    } while (0)

    f32x4 acc[2][2] = {};
    int nk = Kd >> 6;

    STAGE64(0, 0);

    for (int ks = 0; ks < nk; ++ks) {
        int cur = ks & 1;
        if (ks + 1 < nk) {
            STAGE64(cur ^ 1, (ks + 1) << 6);
            asm volatile("s_waitcnt vmcnt(4)" ::: "memory");
        } else {
            asm volatile("s_waitcnt vmcnt(0)" ::: "memory");
        }
        __builtin_amdgcn_s_barrier();

        bf16x8 af[2][2], bfr[2][2];
        #pragma unroll
        for (int kk = 0; kk < 2; ++kk) {
            int slotx = ((kk * 4 + lhi) ^ (lr & 7)) << 3;
            #pragma unroll
            for (int i = 0; i < 2; ++i)
                af[kk][i] = *(const bf16x8*)(AsB + cur * 4096 + (wr * 32 + i * 16 + lr) * 64 + slotx);
            #pragma unroll
            for (int j = 0; j < 2; ++j)
                bfr[kk][j] = *(const bf16x8*)(BsB + cur * 4096 + (wc * 32 + j * 16 + lr) * 64 + slotx);
        }
        asm volatile("s_waitcnt lgkmcnt(0)" ::: "memory");
        __builtin_amdgcn_sched_barrier(0);
        __builtin_amdgcn_s_barrier();

        #pragma unroll
        for (int kk = 0; kk < 2; ++kk)
            #pragma unroll
            for (int i = 0; i < 2; ++i)
                #pragma unroll
                for (int j = 0; j < 2; ++j)
                    acc[i][j] = __builtin_amdgcn_mfma_f32_16x16x32_bf16(af[kk][i], bfr[kk][j], acc[i][j], 0, 0, 0);
    }
    #undef STAGE64

    #pragma unroll
    for (int i = 0; i < 2; ++i) {
        int rbase = row0 + wr * 32 + i * 16 + lhi * 4;
        #pragma unroll
        for (int j = 0; j < 2; ++j) {
            int cidx = col0 + wc * 32 + j * 16 + lr;
            #pragma unroll
            for (int r_ = 0; r_ < 4; ++r_) {
                long idx = czoff + (long)(rbase + r_) * N + cidx;
                if (STORE_BF16) ((unsigned short*)Cv)[idx] = f2bf(acc[i][j][r_]);
                else            ((float*)Cv)[idx] = acc[i][j][r_];
            }
        }
    }
}

// ---------------- deterministic counting sort of rows by mean/64 (one bk per call) ----------------
__device__ void sort_core(char* smem, const float* __restrict__ mean_,
                          int* __restrict__ perm, int bk)
{
    unsigned short (*hist)[257] = (unsigned short(*)[257])smem;
    int* binTot = (int*)(smem + 16448);
    int* binStart = binTot + 32;
    int t = threadIdx.x;
    int bins[8];
    #pragma unroll
    for (int i = 0; i < 8; ++i) {
        float mq = mean_[bk * MM + t * 8 + i];
        int b = (int)(mq * (1.f / 64.f));
        bins[i] = min(31, max(0, b));
    }
    for (int b = 0; b < 32; ++b) hist[b][t] = 0;
    __syncthreads();
    #pragma unroll
    for (int i = 0; i < 8; ++i) hist[bins[i]][t]++;
    __syncthreads();
    int w = t >> 6, l = t & 63;
    for (int b = w * 8; b < w * 8 + 8; ++b) {
        int carry = 0;
        for (int g = 0; g < 4; ++g) {
            int v = (int)hist[b][g * 64 + l];
            int x = v;
            #pragma unroll
            for (int off = 1; off < 64; off <<= 1) {
                int y = __shfl_up(x, off, 64);
                if (l >= off) x += y;
            }
            hist[b][g * 64 + l] = (unsigned short)(x - v + carry);
            carry += __shfl(x, 63, 64);
        }
        if (l == 0) binTot[b] = carry;
    }
    __syncthreads();
    if (t == 0) {
        int s = 0;
        for (int b = 0; b < 32; ++b) { binStart[b] = s; s += binTot[b]; }
    }
    __syncthreads();
    #pragma unroll
    for (int i = 0; i < 8; ++i) {
        int b = bins[i];
        int prior = 0;
        #pragma unroll
        for (int j = 0; j < 8; ++j) if (j < i && bins[j] == b) prior++;
        int pos = binStart[b] + (int)hist[b][t] + prior;
        perm[bk * MM + pos] = t * 8 + i;
    }
}

// ---------------- value GEMM (blocks 0..1023) + sort (blocks 1024..1055) ----------------
__global__ __launch_bounds__(256) void vgemm_sort(
    const unsigned short* __restrict__ Wval_bf, const unsigned short* __restrict__ h_bf,
    unsigned short* __restrict__ hvT,
    const float* __restrict__ mean_, int* __restrict__ perm)
{
    __shared__ __align__(16) char smem[32768];
    int f = blockIdx.x;
    if (f < 1024) {
        int swz = (f & 7) * 128 + (f >> 3);
        int by = swz & 15, r = swz >> 4;
        int bx = r & 31, bz = r >> 5;
        gemm_core64<1>((unsigned short*)smem, (unsigned short*)(smem + 16384),
                       Wval_bf, h_bf, hvT, MM, HSZ, bx, by, bz,
                       0L, (long)MM * HSZ, (long)HSZ * MM);
    } else {
        sort_core(smem, mean_, perm, f - 1024);
    }
}

// ---------------- output GEMM standalone ----------------
__global__ __launch_bounds__(256) void ogemm(
    const unsigned short* __restrict__ att, const unsigned short* __restrict__ Wout_bf,
    float* __restrict__ out)
{
    __shared__ __align__(16) unsigned short As[2][4096];
    __shared__ __align__(16) unsigned short Bs[2][4096];
    int f = blockIdx.x;
    int swz = (f & 7) * 128 + (f >> 3);
    int bx = swz & 15, by = (swz >> 4) & 63;
    gemm_core64<0>(&As[0][0], &Bs[0][0], att, Wout_bf, out, HSZ, HSZ,
                   bx, by, 0, 0L, 0L, 0L);
}

// ---------------- fused Gaussian attention over mean-sorted rows (dynamic k-range) ----------------
__global__ __launch_bounds__(512) void attn_gauss(
    const float* __restrict__ mean_, const float* __restrict__ soft_,
    const int* __restrict__ perm,
    const unsigned short* __restrict__ hvT, unsigned short* __restrict__ att)
{
    __shared__ __align__(16) unsigned short Vs[2][64 * 64];
    __shared__ float red[2][8];
    int flat = blockIdx.x;                   // 0..511
    int swz = (flat & 7) * 64 + (flat >> 3); // XCD-chunked bijection
    int bk = swz >> 4;                       // 0..31
    int qb = swz & 15;                       // 0..15
    int t = threadIdx.x, wid = t >> 6, l = t & 63;
    int b = bk >> 4, head = bk & 15;
    int lr = l & 15, lhi = l >> 4;
    int slot = qb * 128 + wid * 16 + lr;
    int q = perm[bk * MM + slot];
    float mq  = mean_[bk * MM + q];
    float sq  = soft_[bk * MM + q];
    const unsigned short* Vbase = hvT + (long)bk * DH * MM;

    float w = __fsqrt_rn(50.f / sq);
    float lo = mq - w, hi = mq + w;
    #pragma unroll
    for (int off = 1; off < 64; off <<= 1) {
        lo = fminf(lo, __shfl_xor(lo, off, 64));
        hi = fmaxf(hi, __shfl_xor(hi, off, 64));
    }
    if (l == 0) { red[0][wid] = lo; red[1][wid] = hi; }
    __syncthreads();
    float blo = red[0][0], bhi = red[1][0];
    #pragma unroll
    for (int i = 1; i < 8; ++i) {
        blo = fminf(blo, red[0][i]);
        bhi = fmaxf(bhi, red[1][i]);
    }
    blo = fmaxf(blo, 0.f);
    bhi = fmaxf(fminf(bhi, 2047.f), 0.f);
    int kt0 = ((int)blo) >> 6;
    int kt1 = ((int)bhi) >> 6;
    if (kt1 < kt0) kt1 = kt0;

    int sr = t >> 3;
    int sc = (((t & 7) ^ (sr & 7)) * 8);

    f32x4 acc[4] = {};
    float lsum = 0.f;
    int jlane0 = lhi * 8;

    GLOAD_LDS16(Vbase + (long)sr * MM + (kt0 << 6) + sc, &Vs[0][t * 8]);
    __syncthreads();

    for (int kt = kt0; kt <= kt1; ++kt) {
        int cur = (kt - kt0) & 1;
        int k0 = kt << 6;
        if (kt < kt1)
            GLOAD_LDS16(Vbase + (long)sr * MM + (k0 + 64) + sc, &Vs[cur ^ 1][t * 8]);

        float dmin = fmaxf(fmaxf((float)k0 - mq, mq - (float)(k0 + 63)), 0.f);
        bool active = (sq * dmin * dmin) < 50.f;   // exp(-50) ~ 2e-22
        if (__ballot(active)) {
            #pragma unroll
            for (int kk = 0; kk < 64; kk += 32) {
                bf16x8 pfrag;
                float dbase = (float)(k0 + kk + jlane0) - mq;
                #pragma unroll
                for (int jj = 0; jj < 8; ++jj) {
                    float d_ = dbase + (float)jj;
                    float p = __expf(-sq * d_ * d_);
                    lsum += p;
                    pfrag[jj] = (short)f2bf(p);
                }
                int slotx = (((kk >> 3) + lhi) ^ (lr & 7)) << 3;
                #pragma unroll
                for (int df = 0; df < 4; ++df) {
                    bf16x8 vf = *(const bf16x8*)&Vs[cur][(df * 16 + lr) * 64 + slotx];
                    acc[df] = __builtin_amdgcn_mfma_f32_16x16x32_bf16(pfrag, vf, acc[df], 0, 0, 0);
                }
            }
        }
        __syncthreads();
    }

    lsum += __shfl_xor(lsum, 16, 64);
    lsum += __shfl_xor(lsum, 32, 64);

    int slot_base = qb * 128 + wid * 16;
    #pragma unroll
    for (int r_ = 0; r_ < 4; ++r_) {
        int qr = lhi * 4 + r_;
        float inv = 1.f / __shfl(lsum, qr, 64);
        int qo = perm[bk * MM + slot_base + qr];
        long orow = ((long)b * MM + qo) * HSZ + head * DH;
        #pragma unroll
        for (int df = 0; df < 4; ++df)
            att[orow + df * 16 + lr] = f2bf(acc[df][r_] * inv);
    }
}

extern "C" void kernel_launch(void* const* d_in, const int* in_sizes, int n_in,
                              void* d_out, int out_size, void* d_ws, size_t ws_size,
                              hipStream_t stream) {
    (void)in_sizes; (void)n_in; (void)out_size; (void)ws_size;
    const float* h     = (const float*)d_in[0];   // (2, 2048, 1024)
    const float* Wspan = (const float*)d_in[1];   // (32, 1024)
    const float* Wval  = (const float*)d_in[2];   // (1024, 1024)
    const float* Wout  = (const float*)d_in[3];   // (1024, 1024)
    float* out = (float*)d_out;                   // (2, 2048, 1024) f32

    char* ws = (char*)d_ws;
    unsigned short* h_bf    = (unsigned short*)(ws);               // 8 MB
    unsigned short* Wval_bf = (unsigned short*)(ws +  8388608);    // 2 MB
    unsigned short* Wout_bf = (unsigned short*)(ws + 10485760);    // 2 MB
    unsigned short* hvT     = (unsigned short*)(ws + 12582912);    // 8 MB
    unsigned short* att     = (unsigned short*)(ws + 20971520);    // 8 MB
    float*          mean_   = (float*)(ws + 29360128);             // 256 KB
    float*          soft_   = (float*)(ws + 29622272);             // 256 KB
    int*            perm    = (int*)(ws + 29884416);               // 256 KB

    // 1. span split-K MFMA (256 blocks) || h/Wval/Wout converts (1536 blocks)
    pre_fused<<<1792, 256, 0, stream>>>(h, Wspan, Wval, Wout,
                                        mean_, soft_, h_bf, Wval_bf, Wout_bf);

    // 2. value GEMM (1024 blocks, 64x64 tiles) + row sort (32 blocks)
    vgemm_sort<<<1056, 256, 0, stream>>>(Wval_bf, h_bf, hvT, mean_, perm);

    // 3. fused Gaussian attention -> att (B, M, HS) bf16
    attn_gauss<<<512, 512, 0, stream>>>(mean_, soft_, perm, hvT, att);

    // 4. output GEMM: out[b*2048+m][n] = sum_c att[b,m,c] * Wout[n,c]
    ogemm<<<1024, 256, 0, stream>>>(att, Wout_bf, out);
}